// Round 15
// baseline (240.286 us; speedup 1.0000x reference)
//
#include <hip/hip_runtime.h>

#define EPS 1e-7f

constexpr int B = 8, C = 64, H = 256, W = 448;
constexpr int N = H * W;          // 114688
constexpr int P = B * N;          // 917504

constexpr int TS  = 16;           // output tile 16x16
constexpr int NT  = 256;          // one thread per output pixel
constexpr int RW  = 8;            // max source radius (covers |flow| <= 7)
constexpr int WIN = 32;           // TS + 2*RW
constexpr int NW  = WIN * WIN;    // 1024 window positions
constexpr int TGS = 40;           // s_tgt row stride: 4x16 lane block -> all 32 banks 2x (free)
constexpr int K   = 15;           // list capacity; P(cnt>15)~3e-6/px (exact fallback kept)
constexpr int CHB = 8;            // channels per staged chunk (4 fp16x2 planes)
constexpr int NCHUNK = C / CHB;   // 8
constexpr float FMAX = 7.0f;
constexpr int TX = W / TS, TY = H / TS;   // 28, 16
constexpr int TILES = B * TX * TY;        // 3584
constexpr int NXCD = 8;

// Phase-1 layout (words): tgt[32*40=1280] fx[1024] fy[1024] em[1024] pk[15*256=3840] = 8192
// Phase-2 layout: two buffers x 1024 pos x 4 packed words = 8192 words.
// 8192 words = 32,768 B -> exactly 5 blocks/CU.
constexpr int L_TGT = 0, L_FX = 1280, L_FY = 2304, L_EM = 3328, L_PK = 4352;
constexpr int LDS_WORDS = 8192;

typedef __fp16 h2_t __attribute__((ext_vector_type(2)));
static __device__ __forceinline__ unsigned pk2(float a, float b) {
    h2_t h = __builtin_amdgcn_cvt_pkrtz(a, b);
    return __builtin_bit_cast(unsigned, h);
}
static __device__ __forceinline__ float2 up2(unsigned u) {
    h2_t h = __builtin_bit_cast(h2_t, u);
    return make_float2((float)h.x, (float)h.y);
}

__device__ int g_flag;            // #sources with |flow|>FMAX (deterministic per input)

__global__ void zero_flag_k() { g_flag = 0; }

__global__ __launch_bounds__(256) void flag_scan(const float* __restrict__ flow)
{
    int t = blockIdx.x * blockDim.x + threadIdx.x;
    if (t >= P) return;
    int b = t / N, p = t - b * N;
    float fdx = flow[(size_t)(b * 2 + 0) * N + p];
    float fdy = flow[(size_t)(b * 2 + 1) * N + p];
    if (fabsf(fdx) > FMAX || fabsf(fdy) > FMAX) atomicAdd(&g_flag, 1);
}

// Stage 8 channels of the 32x32 window into register set `dst`:
// thread t owns positions 4t..4t+3 (row = t>>3, col = 4*(t&7)); float4, 16B-aligned.
#define STAGE_LOAD(dst, gg)                                                   \
    {                                                                         \
        const int cbase = (gg) * CHB;                                         \
        const int row = tid >> 3;                                             \
        const int sc0 = (tid & 7) * 4;                                        \
        const int sh = ty0 - RW + row;                                        \
        const int sc = tx0 - RW + sc0;                                        \
        const bool v = (sh >= 0) & (sh < H) & (sc >= 0) & (sc < W);           \
        const float* bp = xb + (sh * W + sc);                                 \
        _Pragma("unroll")                                                     \
        for (int ch = 0; ch < CHB; ++ch)                                      \
            dst[ch] = v ? *(const float4*)(bp + (size_t)(cbase + ch) * N)     \
                        : make_float4(0.f, 0.f, 0.f, 0.f);                    \
    }

// Pack register set `src` to fp16 pairs, position-major, XOR-block-swizzled.
#define STAGE_WRITE(src, bufsel)                                              \
    {                                                                         \
        char* base = (char*)lds + (bufsel) * 16384;                           \
        _Pragma("unroll")                                                     \
        for (int k = 0; k < 4; ++k) {                                         \
            const unsigned pos = 4u * (unsigned)tid + (unsigned)k;            \
            const unsigned blk = pos ^ ((pos >> 3) & 7u);                     \
            uint4 wv;                                                         \
            wv.x = pk2(((const float*)&src[0])[k], ((const float*)&src[1])[k]); \
            wv.y = pk2(((const float*)&src[2])[k], ((const float*)&src[3])[k]); \
            wv.z = pk2(((const float*)&src[4])[k], ((const float*)&src[5])[k]); \
            wv.w = pk2(((const float*)&src[6])[k], ((const float*)&src[7])[k]); \
            *(uint4*)(base + blk * 16) = wv;                                  \
        }                                                                     \
    }

// Gather-accumulate 8 channels of chunk gg from LDS buffer bufsel, store out.
#define COMPUTE_STORE(bufsel, gg)                                             \
    {                                                                         \
        const char* bc = (const char*)lds + (bufsel) * 16384;                 \
        float a0 = 0.f, a1 = 0.f, a2 = 0.f, a3 = 0.f;                         \
        float a4 = 0.f, a5 = 0.f, a6 = 0.f, a7 = 0.f;                         \
        _Pragma("unroll")                                                     \
        for (int j = 0; j < K; ++j) {                                         \
            if (j >= kwave) break;              /* wave-uniform branch */     \
            const uint4 v = *(const uint4*)(bc + rsp[j]);                     \
            const float wj = rw_[j];                                          \
            float2 pp;                                                        \
            pp = up2(v.x); a0 = fmaf(wj, pp.x, a0); a1 = fmaf(wj, pp.y, a1);  \
            pp = up2(v.y); a2 = fmaf(wj, pp.x, a2); a3 = fmaf(wj, pp.y, a3);  \
            pp = up2(v.z); a4 = fmaf(wj, pp.x, a4); a5 = fmaf(wj, pp.y, a5);  \
            pp = up2(v.w); a6 = fmaf(wj, pp.x, a6); a7 = fmaf(wj, pp.y, a7);  \
        }                                                                     \
        if (!ovf) {                                                           \
            ob[(size_t)((gg) * CHB + 0) * N] = a0;                            \
            ob[(size_t)((gg) * CHB + 1) * N] = a1;                            \
            ob[(size_t)((gg) * CHB + 2) * N] = a2;                            \
            ob[(size_t)((gg) * CHB + 3) * N] = a3;                            \
            ob[(size_t)((gg) * CHB + 4) * N] = a4;                            \
            ob[(size_t)((gg) * CHB + 5) * N] = a5;                            \
            ob[(size_t)((gg) * CHB + 6) * N] = a6;                            \
            ob[(size_t)((gg) * CHB + 7) * N] = a7;                            \
        }                                                                     \
    }

__global__ __launch_bounds__(NT) void softsplat_fused(
    const float* __restrict__ x,
    const float* __restrict__ flow,
    const float* __restrict__ metric,
    float* __restrict__ out,      // [B, C, N]
    float* __restrict__ den)      // [B, N]
{
    __shared__ float lds[LDS_WORDS];
    unsigned* s_tgt = (unsigned*)(lds + L_TGT);  // [row*40+col]: (ty0+16)<<16 | (tx0+16)
    float*    s_fx  = lds + L_FX;                // frac x  [row*32+col]
    float*    s_fy  = lds + L_FY;                // frac y
    float*    s_em  = lds + L_EM;                // exp(metric)
    unsigned* s_pk  = (unsigned*)(lds + L_PK);   // packed (w_hi22 | pos10)

    // XCD-aware bijective swizzle (TILES % 8 == 0)
    int bid = blockIdx.x;
    bid = (bid % NXCD) * (TILES / NXCD) + bid / NXCD;

    const int b   = bid / (TX * TY);
    const int tp  = bid % (TX * TY);
    const int ty0 = (tp / TX) * TS;
    const int tx0 = (tp % TX) * TS;
    const int tid = threadIdx.x;

    const float* fxg = flow + (size_t)(b * 2 + 0) * N;
    const float* fyg = flow + (size_t)(b * 2 + 1) * N;
    const float* mg  = metric + (size_t)b * N;

    // ---- phase 1a: stage window; precompute target corner + fracs per source ----
    // floor(q+dx+f) == q+dx+floor(f); weight continuous in frac -> diff <= 2e-5.
    float mxx = 0.f, mxy = 0.f;
    for (int i = tid; i < NW; i += NT) {
        const int wy = i >> 5, wx = i & 31;
        const int sh = ty0 - RW + wy, sw = tx0 - RW + wx;
        unsigned t = 0xFFFFFFFFu;                // sentinel: never hits
        if (sh >= 0 && sh < H && sw >= 0 && sw < W) {
            const int sp = sh * W + sw;
            const float a = fxg[sp], bb = fyg[sp];
            if (fabsf(a) <= FMAX && fabsf(bb) <= FMAX) {
                const float xf = floorf(a), yf = floorf(bb);
                const int tx0g = sw + (int)xf + 16;   // [1,470] -> 16 bits
                const int ty0g = sh + (int)yf + 16;
                t = ((unsigned)ty0g << 16) | (unsigned)tx0g;
                s_fx[i] = a - xf;
                s_fy[i] = bb - yf;
                s_em[i] = __expf(mg[sp]);
                mxx = fmaxf(mxx, fabsf(a));
                mxy = fmaxf(mxy, fabsf(bb));
            }
        }
        s_tgt[wy * TGS + wx] = t;
    }
    // block per-axis |flow| max -> rectangular dynamic scan radius (exact:
    // source at axis-offset d contributes only if |flow_axis| >= d-1)
    #pragma unroll
    for (int m = 1; m < 64; m <<= 1) {
        mxx = fmaxf(mxx, __shfl_xor(mxx, m));
        mxy = fmaxf(mxy, __shfl_xor(mxy, m));
    }
    if ((tid & 63) == 0) {
        lds[L_PK + 2 * (tid >> 6) + 0] = mxx;
        lds[L_PK + 2 * (tid >> 6) + 1] = mxy;
    }
    __syncthreads();
    const float Mx = fmaxf(fmaxf(lds[L_PK + 0], lds[L_PK + 2]),
                           fmaxf(lds[L_PK + 4], lds[L_PK + 6]));
    const float My = fmaxf(fmaxf(lds[L_PK + 1], lds[L_PK + 3]),
                           fmaxf(lds[L_PK + 5], lds[L_PK + 7]));
    const int Rx = min(RW, (int)Mx + 1);
    const int Ry = min(RW, (int)My + 1);
    __syncthreads();                        // scratch reads done before pk writes

    const int qxl = tid & (TS - 1), qyl = tid >> 4;
    const int qx = tx0 + qxl, qy = ty0 + qyl;
    const int q  = qy * W + qx;
    const unsigned qx16 = (unsigned)(qx + 16), qy16 = (unsigned)(qy + 16);

    // ---- phase 1b: scan [-Ry,Ry]x[-Rx,Rx]; 7-op reject, full math on hits ----
    int cnt = 0;
    float dacc = 0.f;
    for (int dy = -Ry; dy <= Ry; ++dy) {
        const int lrow = qyl + RW + dy;
        const int trow = lrow * TGS + (qxl + RW);
        for (int dx = -Rx; dx <= Rx; ++dx) {
            const unsigned t = s_tgt[trow + dx];
            const unsigned du = qx16 - (t & 0xFFFFu);
            const unsigned dv = qy16 - (t >> 16);
            if (max(du, dv) > 1u) continue;
            const int fi = lrow * WIN + (qxl + RW + dx);
            const float fxf = s_fx[fi], fyf = s_fy[fi];
            const float wxf = du ? fxf : 1.f - fxf;
            const float wyf = dv ? fyf : 1.f - fyf;
            const float w = wxf * wyf * s_em[fi];
            if (cnt < K)
                s_pk[cnt * NT + tid] = (__float_as_uint(w) & 0xFFFFFC00u) | (unsigned)fi;
            cnt++;
            dacc += w;   // full-precision denominator
        }
    }
    for (int j = cnt; j < K; ++j)
        s_pk[j * NT + tid] = (unsigned)((qyl + RW) * WIN + (qxl + RW));  // w=0 pad

    // wave-uniform loop bound
    int km = cnt;
    #pragma unroll
    for (int m = 1; m < 64; m <<= 1) km = max(km, __shfl_xor(km, m));
    const int kwave = min(K, __builtin_amdgcn_readfirstlane(km));

    const int flag = g_flag;
    const float rn = (flag == 0) ? 1.f / (dacc + EPS) : 1.f;

    const float* xb = x + (size_t)b * C * N;
    float* ob = out + (size_t)b * C * N + q;
    den[(size_t)b * N + q] = dacc;

    // list -> registers; gather index pre-swizzled; weight pre-scaled by rn
    unsigned rsp[K]; float rw_[K];
    #pragma unroll
    for (int j = 0; j < K; ++j) {
        const unsigned pk = s_pk[j * NT + tid];
        const unsigned pos = pk & 0x3FFu;
        rsp[j] = (pos ^ ((pos >> 3) & 7u)) << 4;
        rw_[j] = __uint_as_float(pk & 0xFFFFFC00u) * rn;
    }

    // ---- phase 1c: exact overflow fallback (statistically never) ----
    const bool ovf = (cnt > K);
    if (ovf) {
        for (int c = 0; c < C; ++c) {
            const float* xp = xb + (size_t)c * N;
            float a = 0.f;
            for (int dy = -Ry; dy <= Ry; ++dy) {
                const int lrow = qyl + RW + dy;
                const int trow = lrow * TGS + (qxl + RW);
                for (int dx = -Rx; dx <= Rx; ++dx) {
                    const unsigned t = s_tgt[trow + dx];
                    const unsigned du = qx16 - (t & 0xFFFFu);
                    const unsigned dv = qy16 - (t >> 16);
                    if (max(du, dv) > 1u) continue;
                    const int fi = lrow * WIN + (qxl + RW + dx);
                    const float fxf = s_fx[fi], fyf = s_fy[fi];
                    const float wxf = du ? fxf : 1.f - fxf;
                    const float wyf = dv ? fyf : 1.f - fyf;
                    a = fmaf(wxf * wyf * s_em[fi], xp[(qy + dy) * W + (qx + dx)], a);
                }
            }
            ob[(size_t)c * N] = a * rn;
        }
    }
    __syncthreads();   // phase-1 LDS released; reuse as fp16 staging buffers

    // ---- phase 2: depth-2 prefetch pipeline (named reg sets fr0/fr1) ----
    // chunk g+2's loads issue at chunk g; chunk g+1's LDS write happens a full
    // iteration after its loads -> HBM latency hidden; vmcnt countable since
    // the pending loads target the OTHER register set.
    float4 fr0[CHB], fr1[CHB];
    STAGE_LOAD(fr0, 0)
    STAGE_WRITE(fr0, 0)           // waits only on fr0's loads
    STAGE_LOAD(fr1, 1)            // issue, no wait
    __syncthreads();
    #pragma unroll
    for (int gp = 0; gp < NCHUNK; gp += 2) {
        // even chunk gp: reads buf0
        if (gp + 2 < NCHUNK) STAGE_LOAD(fr0, gp + 2)
        COMPUTE_STORE(0, gp)
        STAGE_WRITE(fr1, 1)       // chunk gp+1 (loaded one iteration ago)
        __syncthreads();
        // odd chunk gp+1: reads buf1
        if (gp + 3 < NCHUNK) STAGE_LOAD(fr1, gp + 3)
        COMPUTE_STORE(1, gp + 1)
        if (gp + 2 < NCHUNK) STAGE_WRITE(fr0, 0)   // chunk gp+2
        __syncthreads();
    }
}

// Sources with |flow|>FMAX (exist iff g_flag!=0): global atomics onto raw accumulators.
__global__ __launch_bounds__(256) void softsplat_outlier(
    const float* __restrict__ x,
    const float* __restrict__ flow,
    const float* __restrict__ metric,
    float* __restrict__ out,
    float* __restrict__ den)
{
    int t = blockIdx.x * blockDim.x + threadIdx.x;
    if (t >= P) return;
    int b = t / N;
    int p = t - b * N;
    float fdx = flow[(size_t)(b * 2 + 0) * N + p];
    float fdy = flow[(size_t)(b * 2 + 1) * N + p];
    if (fabsf(fdx) <= FMAX && fabsf(fdy) <= FMAX) return;

    int h = p / W, w = p - h * W;
    float m = __expf(metric[(size_t)b * N + p]);
    float tx = (float)w + fdx, ty = (float)h + fdy;
    float x0f = floorf(tx), y0f = floorf(ty);
    int x0 = (int)x0f, y0 = (int)y0f, x1 = x0 + 1, y1 = y0 + 1;
    float fx = tx - x0f, fy = ty - y0f;
    float w00 = (1.f - fx) * (1.f - fy), w10 = fx * (1.f - fy);
    float w01 = (1.f - fx) * fy,         w11 = fx * fy;
    bool vx0 = (x0 >= 0) && (x0 < W), vx1 = (x1 >= 0) && (x1 < W);
    bool vy0 = (y0 >= 0) && (y0 < H), vy1 = (y1 >= 0) && (y1 < H);
    int cx0 = min(max(x0, 0), W - 1), cx1 = min(max(x1, 0), W - 1);
    int cy0 = min(max(y0, 0), H - 1), cy1 = min(max(y1, 0), H - 1);
    int i00 = cy0 * W + cx0, i10 = cy0 * W + cx1;
    int i01 = cy1 * W + cx0, i11 = cy1 * W + cx1;
    w00 = (vx0 && vy0) ? w00 * m : 0.f;
    w10 = (vx1 && vy0) ? w10 * m : 0.f;
    w01 = (vx0 && vy1) ? w01 * m : 0.f;
    w11 = (vx1 && vy1) ? w11 * m : 0.f;

    float* denb = den + (size_t)b * N;
    if (w00 != 0.f) atomicAdd(denb + i00, w00);
    if (w10 != 0.f) atomicAdd(denb + i10, w10);
    if (w01 != 0.f) atomicAdd(denb + i01, w01);
    if (w11 != 0.f) atomicAdd(denb + i11, w11);

    const float* xb = x + (size_t)b * C * N + p;
    float* ob = out + (size_t)b * C * N;
    for (int c = 0; c < C; ++c) {
        float v = xb[(size_t)c * N];
        float* o = ob + (size_t)c * N;
        if (w00 != 0.f) atomicAdd(o + i00, v * w00);
        if (w10 != 0.f) atomicAdd(o + i10, v * w10);
        if (w01 != 0.f) atomicAdd(o + i01, v * w01);
        if (w11 != 0.f) atomicAdd(o + i11, v * w11);
    }
}

// Runs only when outliers exist (g_flag!=0); otherwise fused already normalized.
__global__ __launch_bounds__(256) void softsplat_norm(
    float* __restrict__ out, const float* __restrict__ den)
{
    if (g_flag == 0) return;
    size_t t = (size_t)blockIdx.x * blockDim.x + threadIdx.x;  // one float4
    size_t e = t * 4;
    if (e >= (size_t)B * C * N) return;
    size_t b = e / ((size_t)C * N);
    size_t p = (e - b * (size_t)C * N) % N;   // N % 4 == 0

    float4 o = *reinterpret_cast<float4*>(out + e);
    const float4 d = *reinterpret_cast<const float4*>(den + b * N + p);
    o.x = o.x / (d.x + EPS);
    o.y = o.y / (d.y + EPS);
    o.z = o.z / (d.z + EPS);
    o.w = o.w / (d.w + EPS);
    *reinterpret_cast<float4*>(out + e) = o;
}

extern "C" void kernel_launch(void* const* d_in, const int* in_sizes, int n_in,
                              void* d_out, int out_size, void* d_ws, size_t ws_size,
                              hipStream_t stream) {
    const float* x      = (const float*)d_in[0];
    const float* flow   = (const float*)d_in[1];
    const float* metric = (const float*)d_in[2];
    float* out = (float*)d_out;
    float* den = (float*)d_ws;

    zero_flag_k<<<1, 1, 0, stream>>>();
    flag_scan<<<(P + 255) / 256, 256, 0, stream>>>(flow);

    softsplat_fused<<<TILES, NT, 0, stream>>>(x, flow, metric, out, den);

    softsplat_outlier<<<(P + 255) / 256, 256, 0, stream>>>(x, flow, metric, out, den);

    size_t nvec4 = (size_t)B * C * N / 4;
    softsplat_norm<<<(int)((nvec4 + 255) / 256), 256, 0, stream>>>(out, den);
}

// Round 16
// 222.396 us; speedup vs baseline: 1.0804x; 1.0804x over previous
//
#include <hip/hip_runtime.h>

#define EPS 1e-7f

constexpr int B = 8, C = 64, H = 256, W = 448;
constexpr int N = H * W;          // 114688
constexpr int P = B * N;          // 917504

constexpr int TS  = 16;           // output tile 16x16
constexpr int NT  = 256;          // one thread per output pixel
constexpr int RW  = 8;            // max source radius (covers |flow| <= 7)
constexpr int WIN = 32;           // TS + 2*RW
constexpr int NW  = WIN * WIN;    // 1024 window positions
constexpr int K   = 15;           // mailbox capacity; P(cnt>15)~3e-6/px (exact fallback kept)
constexpr int CHB = 8;            // channels per staged chunk (4 fp16x2 planes)
constexpr int NCHUNK = C / CHB;   // 8
constexpr float FMAX = 7.0f;
constexpr int TX = W / TS, TY = H / TS;   // 28, 16
constexpr int TILES = B * TX * TY;        // 3584
constexpr int NXCD = 8;

// Phase-1 layout (words): fx[1024] fy[1024] em[1024] cnt[256] mb[15*256=3840] = 7168
// Phase-2 layout: two buffers x 1024 pos x 4 packed words = 8192 words (dominates).
// 8192 words = 32,768 B -> exactly 5 blocks/CU.
constexpr int L_FX = 0, L_FY = 1024, L_EM = 2048, L_CNT = 3072, L_MB = 3328;
constexpr int LDS_WORDS = 8192;

typedef __fp16 h2_t __attribute__((ext_vector_type(2)));
static __device__ __forceinline__ unsigned pk2(float a, float b) {
    h2_t h = __builtin_amdgcn_cvt_pkrtz(a, b);
    return __builtin_bit_cast(unsigned, h);
}
static __device__ __forceinline__ float2 up2(unsigned u) {
    h2_t h = __builtin_bit_cast(h2_t, u);
    return make_float2((float)h.x, (float)h.y);
}

__device__ int g_flag;            // #sources with |flow|>FMAX (deterministic per input)

__global__ void zero_flag_k() { g_flag = 0; }

__global__ __launch_bounds__(256) void flag_scan(const float* __restrict__ flow)
{
    int t = blockIdx.x * blockDim.x + threadIdx.x;
    if (t >= P) return;
    int b = t / N, p = t - b * N;
    float fdx = flow[(size_t)(b * 2 + 0) * N + p];
    float fdy = flow[(size_t)(b * 2 + 1) * N + p];
    if (fabsf(fdx) > FMAX || fabsf(fdy) > FMAX) atomicAdd(&g_flag, 1);
}

// Stage 8 channels of the 32x32 window into register set `dst`:
// thread t owns positions 4t..4t+3 (row = t>>3, col = 4*(t&7)); float4, 16B-aligned.
#define STAGE_LOAD(dst, gg)                                                   \
    {                                                                         \
        const int cbase = (gg) * CHB;                                         \
        const int row = tid >> 3;                                             \
        const int sc0 = (tid & 7) * 4;                                        \
        const int sh = ty0 - RW + row;                                        \
        const int sc = tx0 - RW + sc0;                                        \
        const bool v = (sh >= 0) & (sh < H) & (sc >= 0) & (sc < W);           \
        const float* bp = xb + (sh * W + sc);                                 \
        _Pragma("unroll")                                                     \
        for (int ch = 0; ch < CHB; ++ch)                                      \
            dst[ch] = v ? *(const float4*)(bp + (size_t)(cbase + ch) * N)     \
                        : make_float4(0.f, 0.f, 0.f, 0.f);                    \
    }

// Pack register set `src` to fp16 pairs, position-major, XOR-block-swizzled.
#define STAGE_WRITE(src, bufsel)                                              \
    {                                                                         \
        char* base = (char*)lds + (bufsel) * 16384;                           \
        _Pragma("unroll")                                                     \
        for (int k = 0; k < 4; ++k) {                                         \
            const unsigned pos = 4u * (unsigned)tid + (unsigned)k;            \
            const unsigned blk = pos ^ ((pos >> 3) & 7u);                     \
            uint4 wv;                                                         \
            wv.x = pk2(((const float*)&src[0])[k], ((const float*)&src[1])[k]); \
            wv.y = pk2(((const float*)&src[2])[k], ((const float*)&src[3])[k]); \
            wv.z = pk2(((const float*)&src[4])[k], ((const float*)&src[5])[k]); \
            wv.w = pk2(((const float*)&src[6])[k], ((const float*)&src[7])[k]); \
            *(uint4*)(base + blk * 16) = wv;                                  \
        }                                                                     \
    }

// Gather-accumulate 8 channels of chunk gg from LDS buffer bufsel, store out.
#define COMPUTE_STORE(bufsel, gg)                                             \
    {                                                                         \
        const char* bc = (const char*)lds + (bufsel) * 16384;                 \
        float a0 = 0.f, a1 = 0.f, a2 = 0.f, a3 = 0.f;                         \
        float a4 = 0.f, a5 = 0.f, a6 = 0.f, a7 = 0.f;                         \
        _Pragma("unroll")                                                     \
        for (int j = 0; j < K; ++j) {                                         \
            if (j >= kwave) break;              /* wave-uniform branch */     \
            const uint4 v = *(const uint4*)(bc + rsp[j]);                     \
            const float wj = rw_[j];                                          \
            float2 pp;                                                        \
            pp = up2(v.x); a0 = fmaf(wj, pp.x, a0); a1 = fmaf(wj, pp.y, a1);  \
            pp = up2(v.y); a2 = fmaf(wj, pp.x, a2); a3 = fmaf(wj, pp.y, a3);  \
            pp = up2(v.z); a4 = fmaf(wj, pp.x, a4); a5 = fmaf(wj, pp.y, a5);  \
            pp = up2(v.w); a6 = fmaf(wj, pp.x, a6); a7 = fmaf(wj, pp.y, a7);  \
        }                                                                     \
        if (!ovf) {                                                           \
            ob[(size_t)((gg) * CHB + 0) * N] = a0;                            \
            ob[(size_t)((gg) * CHB + 1) * N] = a1;                            \
            ob[(size_t)((gg) * CHB + 2) * N] = a2;                            \
            ob[(size_t)((gg) * CHB + 3) * N] = a3;                            \
            ob[(size_t)((gg) * CHB + 4) * N] = a4;                            \
            ob[(size_t)((gg) * CHB + 5) * N] = a5;                            \
            ob[(size_t)((gg) * CHB + 6) * N] = a6;                            \
            ob[(size_t)((gg) * CHB + 7) * N] = a7;                            \
        }                                                                     \
    }

__global__ __launch_bounds__(NT) void softsplat_fused(
    const float* __restrict__ x,
    const float* __restrict__ flow,
    const float* __restrict__ metric,
    float* __restrict__ out,      // [B, C, N]
    float* __restrict__ den)      // [B, N]
{
    __shared__ float lds[LDS_WORDS];
    float*    s_fx  = lds + L_FX;                // frac x  [row*32+col]
    float*    s_fy  = lds + L_FY;                // frac y
    float*    s_em  = lds + L_EM;                // exp(metric)
    int*      s_cnt = (int*)(lds + L_CNT);       // per-output push counters [256]
    unsigned* s_mb  = (unsigned*)(lds + L_MB);   // mailboxes [K][256]: (cr<<10 | fi)

    // XCD-aware bijective swizzle (TILES % 8 == 0)
    int bid = blockIdx.x;
    bid = (bid % NXCD) * (TILES / NXCD) + bid / NXCD;

    const int b   = bid / (TX * TY);
    const int tp  = bid % (TX * TY);
    const int ty0 = (tp / TX) * TS;
    const int tx0 = (tp % TX) * TS;
    const int tid = threadIdx.x;

    const float* fxg = flow + (size_t)(b * 2 + 0) * N;
    const float* fyg = flow + (size_t)(b * 2 + 1) * N;
    const float* mg  = metric + (size_t)b * N;

    s_cnt[tid] = 0;
    __syncthreads();

    // ---- phase 1a: stage window + PUSH each source's <=4 covered outputs ----
    // floor(q+dx+f) == q+dx+floor(f); weight continuous in frac -> diff <= 2e-5.
    for (int i = tid; i < NW; i += NT) {
        const int wy = i >> 5, wx = i & 31;
        const int sh = ty0 - RW + wy, sw = tx0 - RW + wx;
        if (sh >= 0 && sh < H && sw >= 0 && sw < W) {
            const int sp = sh * W + sw;
            const float a = fxg[sp], bb = fyg[sp];
            if (fabsf(a) <= FMAX && fabsf(bb) <= FMAX) {
                const float xf = floorf(a), yf = floorf(bb);
                s_fx[i] = a - xf;
                s_fy[i] = bb - yf;
                s_em[i] = __expf(mg[sp]);
                const int ltx = sw + (int)xf - tx0;   // local corner-0 coords
                const int lty = sh + (int)yf - ty0;
                #pragma unroll
                for (int cr = 0; cr < 4; ++cr) {
                    const int cx = ltx + (cr & 1), cy = lty + (cr >> 1);
                    if ((unsigned)cx < (unsigned)TS && (unsigned)cy < (unsigned)TS) {
                        const int oid = cy * TS + cx;
                        const int slot = atomicAdd(&s_cnt[oid], 1);
                        if (slot < K) s_mb[slot * NT + oid] = (unsigned)(i | (cr << 10));
                    }
                }
            }
        }
    }
    __syncthreads();

    const int qxl = tid & (TS - 1), qyl = tid >> 4;
    const int qx = tx0 + qxl, qy = ty0 + qyl;
    const int q  = qy * W + qx;

    // ---- consume: mailbox -> register list; dacc = sum of weights ----
    const int cnt = s_cnt[tid];
    const int kk  = min(cnt, K);
    int km = cnt;
    #pragma unroll
    for (int m = 1; m < 64; m <<= 1) km = max(km, __shfl_xor(km, m));
    const int kwave = min(K, __builtin_amdgcn_readfirstlane(km));

    float dacc = 0.f;
    unsigned rsp[K]; float rw_[K];
    #pragma unroll
    for (int j = 0; j < K; ++j) {
        const bool live = j < kk;
        const unsigned pk = s_mb[j * NT + tid];   // garbage when !live; masked below
        const unsigned fi = pk & 1023u;
        const unsigned cr = (pk >> 10) & 3u;
        const float fxf = s_fx[fi], fyf = s_fy[fi];
        const float wxf = (cr & 1u) ? fxf : 1.f - fxf;
        const float wyf = (cr >> 1) ? fyf : 1.f - fyf;
        const float w = live ? wxf * wyf * s_em[fi] : 0.f;   // select kills garbage/NaN
        dacc += w;
        rw_[j] = w;
        const unsigned pos = live ? fi : (unsigned)((qyl + RW) * WIN + (qxl + RW));
        rsp[j] = (pos ^ ((pos >> 3) & 7u)) << 4;
    }

    // ---- exact overflow fallback (statistically never): self-contained rescan ----
    const bool ovf = (cnt > K);
    if (ovf) {
        dacc = 0.f;
        for (int dy = -RW; dy <= RW; ++dy) {
            for (int dx = -RW; dx <= RW; ++dx) {
                const int sh = qy + dy, sw = qx + dx;
                if (sh < 0 || sh >= H || sw < 0 || sw >= W) continue;
                const int sp = sh * W + sw;
                const float a = fxg[sp], bb = fyg[sp];
                if (fabsf(a) > FMAX || fabsf(bb) > FMAX) continue;
                const float xf = floorf(a), yf = floorf(bb);
                const int du = qx - (sw + (int)xf); if ((unsigned)du > 1u) continue;
                const int dv = qy - (sh + (int)yf); if ((unsigned)dv > 1u) continue;
                const float wxf = du ? a - xf : 1.f - (a - xf);
                const float wyf = dv ? bb - yf : 1.f - (bb - yf);
                dacc += wxf * wyf * __expf(mg[sp]);
            }
        }
    }
    den[(size_t)b * N + q] = dacc;

    const float rn = (g_flag == 0) ? 1.f / (dacc + EPS) : 1.f;
    #pragma unroll
    for (int j = 0; j < K; ++j) rw_[j] *= rn;

    const float* xb = x + (size_t)b * C * N;
    float* ob = out + (size_t)b * C * N + q;

    if (ovf) {   // rare: direct global gather for all channels
        for (int c = 0; c < C; ++c) {
            const float* xp = xb + (size_t)c * N;
            float acc = 0.f;
            for (int dy = -RW; dy <= RW; ++dy) {
                for (int dx = -RW; dx <= RW; ++dx) {
                    const int sh = qy + dy, sw = qx + dx;
                    if (sh < 0 || sh >= H || sw < 0 || sw >= W) continue;
                    const int sp = sh * W + sw;
                    const float a = fxg[sp], bb = fyg[sp];
                    if (fabsf(a) > FMAX || fabsf(bb) > FMAX) continue;
                    const float xf = floorf(a), yf = floorf(bb);
                    const int du = qx - (sw + (int)xf); if ((unsigned)du > 1u) continue;
                    const int dv = qy - (sh + (int)yf); if ((unsigned)dv > 1u) continue;
                    const float wxf = du ? a - xf : 1.f - (a - xf);
                    const float wyf = dv ? bb - yf : 1.f - (bb - yf);
                    acc = fmaf(wxf * wyf * __expf(mg[sp]), xp[sp], acc);
                }
            }
            ob[(size_t)c * N] = acc * rn;
        }
    }
    __syncthreads();   // phase-1 LDS released; reuse as fp16 staging buffers

    // ---- phase 2: depth-2 prefetch pipeline (named reg sets fr0/fr1) ----
    float4 fr0[CHB], fr1[CHB];
    STAGE_LOAD(fr0, 0)
    STAGE_WRITE(fr0, 0)
    STAGE_LOAD(fr1, 1)
    __syncthreads();
    #pragma unroll
    for (int gp = 0; gp < NCHUNK; gp += 2) {
        if (gp + 2 < NCHUNK) STAGE_LOAD(fr0, gp + 2)
        COMPUTE_STORE(0, gp)
        STAGE_WRITE(fr1, 1)
        __syncthreads();
        if (gp + 3 < NCHUNK) STAGE_LOAD(fr1, gp + 3)
        COMPUTE_STORE(1, gp + 1)
        if (gp + 2 < NCHUNK) STAGE_WRITE(fr0, 0)
        __syncthreads();
    }
}

// Sources with |flow|>FMAX (exist iff g_flag!=0): global atomics onto raw accumulators.
__global__ __launch_bounds__(256) void softsplat_outlier(
    const float* __restrict__ x,
    const float* __restrict__ flow,
    const float* __restrict__ metric,
    float* __restrict__ out,
    float* __restrict__ den)
{
    int t = blockIdx.x * blockDim.x + threadIdx.x;
    if (t >= P) return;
    int b = t / N;
    int p = t - b * N;
    float fdx = flow[(size_t)(b * 2 + 0) * N + p];
    float fdy = flow[(size_t)(b * 2 + 1) * N + p];
    if (fabsf(fdx) <= FMAX && fabsf(fdy) <= FMAX) return;

    int h = p / W, w = p - h * W;
    float m = __expf(metric[(size_t)b * N + p]);
    float tx = (float)w + fdx, ty = (float)h + fdy;
    float x0f = floorf(tx), y0f = floorf(ty);
    int x0 = (int)x0f, y0 = (int)y0f, x1 = x0 + 1, y1 = y0 + 1;
    float fx = tx - x0f, fy = ty - y0f;
    float w00 = (1.f - fx) * (1.f - fy), w10 = fx * (1.f - fy);
    float w01 = (1.f - fx) * fy,         w11 = fx * fy;
    bool vx0 = (x0 >= 0) && (x0 < W), vx1 = (x1 >= 0) && (x1 < W);
    bool vy0 = (y0 >= 0) && (y0 < H), vy1 = (y1 >= 0) && (y1 < H);
    int cx0 = min(max(x0, 0), W - 1), cx1 = min(max(x1, 0), W - 1);
    int cy0 = min(max(y0, 0), H - 1), cy1 = min(max(y1, 0), H - 1);
    int i00 = cy0 * W + cx0, i10 = cy0 * W + cx1;
    int i01 = cy1 * W + cx0, i11 = cy1 * W + cx1;
    w00 = (vx0 && vy0) ? w00 * m : 0.f;
    w10 = (vx1 && vy0) ? w10 * m : 0.f;
    w01 = (vx0 && vy1) ? w01 * m : 0.f;
    w11 = (vx1 && vy1) ? w11 * m : 0.f;

    float* denb = den + (size_t)b * N;
    if (w00 != 0.f) atomicAdd(denb + i00, w00);
    if (w10 != 0.f) atomicAdd(denb + i10, w10);
    if (w01 != 0.f) atomicAdd(denb + i01, w01);
    if (w11 != 0.f) atomicAdd(denb + i11, w11);

    const float* xb = x + (size_t)b * C * N + p;
    float* ob = out + (size_t)b * C * N;
    for (int c = 0; c < C; ++c) {
        float v = xb[(size_t)c * N];
        float* o = ob + (size_t)c * N;
        if (w00 != 0.f) atomicAdd(o + i00, v * w00);
        if (w10 != 0.f) atomicAdd(o + i10, v * w10);
        if (w01 != 0.f) atomicAdd(o + i01, v * w01);
        if (w11 != 0.f) atomicAdd(o + i11, v * w11);
    }
}

// Runs only when outliers exist (g_flag!=0); otherwise fused already normalized.
__global__ __launch_bounds__(256) void softsplat_norm(
    float* __restrict__ out, const float* __restrict__ den)
{
    if (g_flag == 0) return;
    size_t t = (size_t)blockIdx.x * blockDim.x + threadIdx.x;  // one float4
    size_t e = t * 4;
    if (e >= (size_t)B * C * N) return;
    size_t b = e / ((size_t)C * N);
    size_t p = (e - b * (size_t)C * N) % N;   // N % 4 == 0

    float4 o = *reinterpret_cast<float4*>(out + e);
    const float4 d = *reinterpret_cast<const float4*>(den + b * N + p);
    o.x = o.x / (d.x + EPS);
    o.y = o.y / (d.y + EPS);
    o.z = o.z / (d.z + EPS);
    o.w = o.w / (d.w + EPS);
    *reinterpret_cast<float4*>(out + e) = o;
}

extern "C" void kernel_launch(void* const* d_in, const int* in_sizes, int n_in,
                              void* d_out, int out_size, void* d_ws, size_t ws_size,
                              hipStream_t stream) {
    const float* x      = (const float*)d_in[0];
    const float* flow   = (const float*)d_in[1];
    const float* metric = (const float*)d_in[2];
    float* out = (float*)d_out;
    float* den = (float*)d_ws;

    zero_flag_k<<<1, 1, 0, stream>>>();
    flag_scan<<<(P + 255) / 256, 256, 0, stream>>>(flow);

    softsplat_fused<<<TILES, NT, 0, stream>>>(x, flow, metric, out, den);

    softsplat_outlier<<<(P + 255) / 256, 256, 0, stream>>>(x, flow, metric, out, den);

    size_t nvec4 = (size_t)B * C * N / 4;
    softsplat_norm<<<(int)((nvec4 + 255) / 256), 256, 0, stream>>>(out, den);
}

// Round 17
// 221.665 us; speedup vs baseline: 1.0840x; 1.0033x over previous
//
#include <hip/hip_runtime.h>

#define EPS 1e-7f

constexpr int B = 8, C = 64, H = 256, W = 448;
constexpr int N = H * W;          // 114688
constexpr int P = B * N;          // 917504

constexpr int TS  = 16;           // output tile 16x16
constexpr int NT  = 256;          // one thread per output pixel
constexpr int RW  = 8;            // max source radius (covers |flow| <= 7)
constexpr int WIN = 32;           // TS + 2*RW
constexpr int NW  = WIN * WIN;    // 1024 window positions
constexpr int K   = 15;           // mailbox capacity; P(cnt>15)~3e-6/px (exact fallback kept)
constexpr int CHB = 8;            // channels per staged chunk (4 fp16x2 planes)
constexpr int NCHUNK = C / CHB;   // 8
constexpr float FMAX = 7.0f;
constexpr int TX = W / TS, TY = H / TS;   // 28, 16
constexpr int TILES = B * TX * TY;        // 3584
constexpr int NXCD = 8;

// Phase-1 layout (words): cnt[256] mb[15*256=3840] = 4096 (mailbox carries the
// final packed (w_hi22 | pos10) -- no fx/fy/em staging needed at all).
// Phase-2 layout: two buffers x 1024 pos x 4 packed words = 8192 words (dominates).
// 8192 words = 32,768 B.
constexpr int L_CNT = 0, L_MB = 256;
constexpr int LDS_WORDS = 8192;

typedef __fp16 h2_t __attribute__((ext_vector_type(2)));
static __device__ __forceinline__ unsigned pk2(float a, float b) {
    h2_t h = __builtin_amdgcn_cvt_pkrtz(a, b);
    return __builtin_bit_cast(unsigned, h);
}
static __device__ __forceinline__ float2 up2(unsigned u) {
    h2_t h = __builtin_bit_cast(h2_t, u);
    return make_float2((float)h.x, (float)h.y);
}

__device__ int g_flag;            // #sources with |flow|>FMAX (deterministic per input)

__global__ void zero_flag_k() { g_flag = 0; }

__global__ __launch_bounds__(256) void flag_scan(const float* __restrict__ flow)
{
    int t = blockIdx.x * blockDim.x + threadIdx.x;
    if (t >= P) return;
    int b = t / N, p = t - b * N;
    float fdx = flow[(size_t)(b * 2 + 0) * N + p];
    float fdy = flow[(size_t)(b * 2 + 1) * N + p];
    if (fabsf(fdx) > FMAX || fabsf(fdy) > FMAX) atomicAdd(&g_flag, 1);
}

// Stage 8 channels of the 32x32 window into register set `dst`:
// thread t owns positions 4t..4t+3 (row = t>>3, col = 4*(t&7)); float4, 16B-aligned.
#define STAGE_LOAD(dst, gg)                                                   \
    {                                                                         \
        const int cbase = (gg) * CHB;                                         \
        const int row = tid >> 3;                                             \
        const int sc0 = (tid & 7) * 4;                                        \
        const int sh = ty0 - RW + row;                                        \
        const int sc = tx0 - RW + sc0;                                        \
        const bool v = (sh >= 0) & (sh < H) & (sc >= 0) & (sc < W);           \
        const float* bp = xb + (sh * W + sc);                                 \
        _Pragma("unroll")                                                     \
        for (int ch = 0; ch < CHB; ++ch)                                      \
            dst[ch] = v ? *(const float4*)(bp + (size_t)(cbase + ch) * N)     \
                        : make_float4(0.f, 0.f, 0.f, 0.f);                    \
    }

// Pack register set `src` to fp16 pairs, position-major, XOR-block-swizzled.
#define STAGE_WRITE(src, bufsel)                                              \
    {                                                                         \
        char* base = (char*)lds + (bufsel) * 16384;                           \
        _Pragma("unroll")                                                     \
        for (int k = 0; k < 4; ++k) {                                         \
            const unsigned pos = 4u * (unsigned)tid + (unsigned)k;            \
            const unsigned blk = pos ^ ((pos >> 3) & 7u);                     \
            uint4 wv;                                                         \
            wv.x = pk2(((const float*)&src[0])[k], ((const float*)&src[1])[k]); \
            wv.y = pk2(((const float*)&src[2])[k], ((const float*)&src[3])[k]); \
            wv.z = pk2(((const float*)&src[4])[k], ((const float*)&src[5])[k]); \
            wv.w = pk2(((const float*)&src[6])[k], ((const float*)&src[7])[k]); \
            *(uint4*)(base + blk * 16) = wv;                                  \
        }                                                                     \
    }

// Gather-accumulate 8 channels of chunk gg from LDS buffer bufsel, store out.
#define COMPUTE_STORE(bufsel, gg)                                             \
    {                                                                         \
        const char* bc = (const char*)lds + (bufsel) * 16384;                 \
        float a0 = 0.f, a1 = 0.f, a2 = 0.f, a3 = 0.f;                         \
        float a4 = 0.f, a5 = 0.f, a6 = 0.f, a7 = 0.f;                         \
        _Pragma("unroll")                                                     \
        for (int j = 0; j < K; ++j) {                                         \
            if (j >= kwave) break;              /* wave-uniform branch */     \
            const uint4 v = *(const uint4*)(bc + rsp[j]);                     \
            const float wj = rw_[j];                                          \
            float2 pp;                                                        \
            pp = up2(v.x); a0 = fmaf(wj, pp.x, a0); a1 = fmaf(wj, pp.y, a1);  \
            pp = up2(v.y); a2 = fmaf(wj, pp.x, a2); a3 = fmaf(wj, pp.y, a3);  \
            pp = up2(v.z); a4 = fmaf(wj, pp.x, a4); a5 = fmaf(wj, pp.y, a5);  \
            pp = up2(v.w); a6 = fmaf(wj, pp.x, a6); a7 = fmaf(wj, pp.y, a7);  \
        }                                                                     \
        if (!ovf) {                                                           \
            ob[(size_t)((gg) * CHB + 0) * N] = a0;                            \
            ob[(size_t)((gg) * CHB + 1) * N] = a1;                            \
            ob[(size_t)((gg) * CHB + 2) * N] = a2;                            \
            ob[(size_t)((gg) * CHB + 3) * N] = a3;                            \
            ob[(size_t)((gg) * CHB + 4) * N] = a4;                            \
            ob[(size_t)((gg) * CHB + 5) * N] = a5;                            \
            ob[(size_t)((gg) * CHB + 6) * N] = a6;                            \
            ob[(size_t)((gg) * CHB + 7) * N] = a7;                            \
        }                                                                     \
    }

__global__ __launch_bounds__(NT) void softsplat_fused(
    const float* __restrict__ x,
    const float* __restrict__ flow,
    const float* __restrict__ metric,
    float* __restrict__ out,      // [B, C, N]
    float* __restrict__ den)      // [B, N]
{
    __shared__ float lds[LDS_WORDS];
    int*      s_cnt = (int*)(lds + L_CNT);       // per-output push counters [256]
    unsigned* s_mb  = (unsigned*)(lds + L_MB);   // mailboxes [K][256]: (w_hi22 | pos10)

    // XCD-aware bijective swizzle (TILES % 8 == 0)
    int bid = blockIdx.x;
    bid = (bid % NXCD) * (TILES / NXCD) + bid / NXCD;

    const int b   = bid / (TX * TY);
    const int tp  = bid % (TX * TY);
    const int ty0 = (tp / TX) * TS;
    const int tx0 = (tp % TX) * TS;
    const int tid = threadIdx.x;

    const float* fxg = flow + (size_t)(b * 2 + 0) * N;
    const float* fyg = flow + (size_t)(b * 2 + 1) * N;
    const float* mg  = metric + (size_t)b * N;

    s_cnt[tid] = 0;
    __syncthreads();

    // ---- phase 1: PUSH -- each source computes its <=4 corner weights and
    // deposits the final packed (weight | window-pos) into the destination
    // outputs' mailboxes. No fx/fy/em staging at all.
    // floor(q+dx+f) == q+dx+floor(f); weight continuous in frac -> diff <= 2e-5.
    for (int i = tid; i < NW; i += NT) {
        const int wy = i >> 5, wx = i & 31;
        const int sh = ty0 - RW + wy, sw = tx0 - RW + wx;
        if (sh >= 0 && sh < H && sw >= 0 && sw < W) {
            const int sp = sh * W + sw;
            const float a = fxg[sp], bb = fyg[sp];
            if (fabsf(a) <= FMAX && fabsf(bb) <= FMAX) {
                const float xf = floorf(a), yf = floorf(bb);
                const float fx = a - xf, fy = bb - yf;
                const float em = __expf(mg[sp]);
                const int ltx = sw + (int)xf - tx0;   // local corner-0 coords
                const int lty = sh + (int)yf - ty0;
                #pragma unroll
                for (int cr = 0; cr < 4; ++cr) {
                    const int cx = ltx + (cr & 1), cy = lty + (cr >> 1);
                    if ((unsigned)cx < (unsigned)TS && (unsigned)cy < (unsigned)TS) {
                        const float wxf = (cr & 1) ? fx : 1.f - fx;
                        const float wyf = (cr >> 1) ? fy : 1.f - fy;
                        const float w = wxf * wyf * em;
                        const int oid = cy * TS + cx;
                        const int slot = atomicAdd(&s_cnt[oid], 1);
                        if (slot < K)
                            s_mb[slot * NT + oid] =
                                (__float_as_uint(w) & 0xFFFFFC00u) | (unsigned)i;
                    }
                }
            }
        }
    }
    __syncthreads();

    const int qxl = tid & (TS - 1), qyl = tid >> 4;
    const int qx = tx0 + qxl, qy = ty0 + qyl;
    const int q  = qy * W + qx;

    // ---- consume: mailbox -> register list; dacc = sum of weights ----
    const int cnt = s_cnt[tid];
    const int kk  = min(cnt, K);
    int km = cnt;
    #pragma unroll
    for (int m = 1; m < 64; m <<= 1) km = max(km, __shfl_xor(km, m));
    const int kwave = min(K, __builtin_amdgcn_readfirstlane(km));

    float dacc = 0.f;
    unsigned rsp[K]; float rw_[K];
    #pragma unroll
    for (int j = 0; j < K; ++j) {
        const bool live = j < kk;
        const unsigned pk = s_mb[j * NT + tid];   // garbage when !live; masked below
        const float w = live ? __uint_as_float(pk & 0xFFFFFC00u) : 0.f;
        dacc += w;
        rw_[j] = w;
        const unsigned pos = live ? (pk & 1023u)
                                  : (unsigned)((qyl + RW) * WIN + (qxl + RW));
        rsp[j] = (pos ^ ((pos >> 3) & 7u)) << 4;
    }

    // ---- exact overflow fallback (statistically never): self-contained rescan ----
    const bool ovf = (cnt > K);
    if (ovf) {
        dacc = 0.f;
        for (int dy = -RW; dy <= RW; ++dy) {
            for (int dx = -RW; dx <= RW; ++dx) {
                const int sh = qy + dy, sw = qx + dx;
                if (sh < 0 || sh >= H || sw < 0 || sw >= W) continue;
                const int sp = sh * W + sw;
                const float a = fxg[sp], bb = fyg[sp];
                if (fabsf(a) > FMAX || fabsf(bb) > FMAX) continue;
                const float xf = floorf(a), yf = floorf(bb);
                const int du = qx - (sw + (int)xf); if ((unsigned)du > 1u) continue;
                const int dv = qy - (sh + (int)yf); if ((unsigned)dv > 1u) continue;
                const float wxf = du ? a - xf : 1.f - (a - xf);
                const float wyf = dv ? bb - yf : 1.f - (bb - yf);
                dacc += wxf * wyf * __expf(mg[sp]);
            }
        }
    }
    den[(size_t)b * N + q] = dacc;

    const float rn = (g_flag == 0) ? 1.f / (dacc + EPS) : 1.f;
    #pragma unroll
    for (int j = 0; j < K; ++j) rw_[j] *= rn;

    const float* xb = x + (size_t)b * C * N;
    float* ob = out + (size_t)b * C * N + q;

    if (ovf) {   // rare: direct global gather for all channels
        for (int c = 0; c < C; ++c) {
            const float* xp = xb + (size_t)c * N;
            float acc = 0.f;
            for (int dy = -RW; dy <= RW; ++dy) {
                for (int dx = -RW; dx <= RW; ++dx) {
                    const int sh = qy + dy, sw = qx + dx;
                    if (sh < 0 || sh >= H || sw < 0 || sw >= W) continue;
                    const int sp = sh * W + sw;
                    const float a = fxg[sp], bb = fyg[sp];
                    if (fabsf(a) > FMAX || fabsf(bb) > FMAX) continue;
                    const float xf = floorf(a), yf = floorf(bb);
                    const int du = qx - (sw + (int)xf); if ((unsigned)du > 1u) continue;
                    const int dv = qy - (sh + (int)yf); if ((unsigned)dv > 1u) continue;
                    const float wxf = du ? a - xf : 1.f - (a - xf);
                    const float wyf = dv ? bb - yf : 1.f - (bb - yf);
                    acc = fmaf(wxf * wyf * __expf(mg[sp]), xp[sp], acc);
                }
            }
            ob[(size_t)c * N] = acc * rn;
        }
    }
    __syncthreads();   // phase-1 LDS (cnt+mb) released; reuse as staging buffers

    // ---- phase 2: depth-2 prefetch pipeline (named reg sets fr0/fr1) ----
    float4 fr0[CHB], fr1[CHB];
    STAGE_LOAD(fr0, 0)
    STAGE_WRITE(fr0, 0)
    STAGE_LOAD(fr1, 1)
    __syncthreads();
    #pragma unroll
    for (int gp = 0; gp < NCHUNK; gp += 2) {
        if (gp + 2 < NCHUNK) STAGE_LOAD(fr0, gp + 2)
        COMPUTE_STORE(0, gp)
        STAGE_WRITE(fr1, 1)
        __syncthreads();
        if (gp + 3 < NCHUNK) STAGE_LOAD(fr1, gp + 3)
        COMPUTE_STORE(1, gp + 1)
        if (gp + 2 < NCHUNK) STAGE_WRITE(fr0, 0)
        __syncthreads();
    }
}

// Sources with |flow|>FMAX (exist iff g_flag!=0): global atomics onto raw accumulators.
__global__ __launch_bounds__(256) void softsplat_outlier(
    const float* __restrict__ x,
    const float* __restrict__ flow,
    const float* __restrict__ metric,
    float* __restrict__ out,
    float* __restrict__ den)
{
    int t = blockIdx.x * blockDim.x + threadIdx.x;
    if (t >= P) return;
    int b = t / N;
    int p = t - b * N;
    float fdx = flow[(size_t)(b * 2 + 0) * N + p];
    float fdy = flow[(size_t)(b * 2 + 1) * N + p];
    if (fabsf(fdx) <= FMAX && fabsf(fdy) <= FMAX) return;

    int h = p / W, w = p - h * W;
    float m = __expf(metric[(size_t)b * N + p]);
    float tx = (float)w + fdx, ty = (float)h + fdy;
    float x0f = floorf(tx), y0f = floorf(ty);
    int x0 = (int)x0f, y0 = (int)y0f, x1 = x0 + 1, y1 = y0 + 1;
    float fx = tx - x0f, fy = ty - y0f;
    float w00 = (1.f - fx) * (1.f - fy), w10 = fx * (1.f - fy);
    float w01 = (1.f - fx) * fy,         w11 = fx * fy;
    bool vx0 = (x0 >= 0) && (x0 < W), vx1 = (x1 >= 0) && (x1 < W);
    bool vy0 = (y0 >= 0) && (y0 < H), vy1 = (y1 >= 0) && (y1 < H);
    int cx0 = min(max(x0, 0), W - 1), cx1 = min(max(x1, 0), W - 1);
    int cy0 = min(max(y0, 0), H - 1), cy1 = min(max(y1, 0), H - 1);
    int i00 = cy0 * W + cx0, i10 = cy0 * W + cx1;
    int i01 = cy1 * W + cx0, i11 = cy1 * W + cx1;
    w00 = (vx0 && vy0) ? w00 * m : 0.f;
    w10 = (vx1 && vy0) ? w10 * m : 0.f;
    w01 = (vx0 && vy1) ? w01 * m : 0.f;
    w11 = (vx1 && vy1) ? w11 * m : 0.f;

    float* denb = den + (size_t)b * N;
    if (w00 != 0.f) atomicAdd(denb + i00, w00);
    if (w10 != 0.f) atomicAdd(denb + i10, w10);
    if (w01 != 0.f) atomicAdd(denb + i01, w01);
    if (w11 != 0.f) atomicAdd(denb + i11, w11);

    const float* xb = x + (size_t)b * C * N + p;
    float* ob = out + (size_t)b * C * N;
    for (int c = 0; c < C; ++c) {
        float v = xb[(size_t)c * N];
        float* o = ob + (size_t)c * N;
        if (w00 != 0.f) atomicAdd(o + i00, v * w00);
        if (w10 != 0.f) atomicAdd(o + i10, v * w10);
        if (w01 != 0.f) atomicAdd(o + i01, v * w01);
        if (w11 != 0.f) atomicAdd(o + i11, v * w11);
    }
}

// Runs only when outliers exist (g_flag!=0); otherwise fused already normalized.
__global__ __launch_bounds__(256) void softsplat_norm(
    float* __restrict__ out, const float* __restrict__ den)
{
    if (g_flag == 0) return;
    size_t t = (size_t)blockIdx.x * blockDim.x + threadIdx.x;  // one float4
    size_t e = t * 4;
    if (e >= (size_t)B * C * N) return;
    size_t b = e / ((size_t)C * N);
    size_t p = (e - b * (size_t)C * N) % N;   // N % 4 == 0

    float4 o = *reinterpret_cast<float4*>(out + e);
    const float4 d = *reinterpret_cast<const float4*>(den + b * N + p);
    o.x = o.x / (d.x + EPS);
    o.y = o.y / (d.y + EPS);
    o.z = o.z / (d.z + EPS);
    o.w = o.w / (d.w + EPS);
    *reinterpret_cast<float4*>(out + e) = o;
}

extern "C" void kernel_launch(void* const* d_in, const int* in_sizes, int n_in,
                              void* d_out, int out_size, void* d_ws, size_t ws_size,
                              hipStream_t stream) {
    const float* x      = (const float*)d_in[0];
    const float* flow   = (const float*)d_in[1];
    const float* metric = (const float*)d_in[2];
    float* out = (float*)d_out;
    float* den = (float*)d_ws;

    zero_flag_k<<<1, 1, 0, stream>>>();
    flag_scan<<<(P + 255) / 256, 256, 0, stream>>>(flow);

    softsplat_fused<<<TILES, NT, 0, stream>>>(x, flow, metric, out, den);

    softsplat_outlier<<<(P + 255) / 256, 256, 0, stream>>>(x, flow, metric, out, den);

    size_t nvec4 = (size_t)B * C * N / 4;
    softsplat_norm<<<(int)((nvec4 + 255) / 256), 256, 0, stream>>>(out, den);
}